// Round 5
// baseline (728.499 us; speedup 1.0000x reference)
//
#include <hip/hip_runtime.h>
#include <hip/hip_fp16.h>
#include <math.h>

#define NN 100000
#define EE 1600000
#define ET (EE + NN)   // 1,700,000 edges incl self-loops
#define FIN 128
#define D1 64          // H1*C1
#define H1 8
#define C1 8
#define C2 40
#define NEG 0.2f
#define EPSV 1e-16f

__device__ __forceinline__ void edge_sd(int e, const int* __restrict__ ei, int& s, int& d) {
  if (e < EE) { s = ei[e]; d = ei[EE + e]; }
  else        { s = e - EE; d = s; }
}

// ---------- CSR build ----------
__global__ void deg_kernel(const int* __restrict__ ei, int* __restrict__ deg) {
  int e = blockIdx.x * 256 + threadIdx.x;
  if (e >= ET) return;
  int s, d; edge_sd(e, ei, s, d);
  atomicAdd(&deg[d], 1);
}

#define NB_SCAN ((NN + 1023) / 1024)
__global__ __launch_bounds__(256) void scan1_kernel(const int* __restrict__ deg,
                                                    int* __restrict__ rowptr,
                                                    int* __restrict__ partial) {
  __shared__ int sd[256];
  int b = blockIdx.x, t = threadIdx.x;
  int base = b * 1024 + t * 4;
  int v[4], s = 0;
#pragma unroll
  for (int j = 0; j < 4; ++j) { int idx = base + j; v[j] = (idx < NN) ? deg[idx] : 0; s += v[j]; }
  sd[t] = s;
  __syncthreads();
  for (int off = 1; off < 256; off <<= 1) {
    int x = sd[t];
    int y = (t >= off) ? sd[t - off] : 0;
    __syncthreads();
    sd[t] = x + y;
    __syncthreads();
  }
  int run = sd[t] - s;
#pragma unroll
  for (int j = 0; j < 4; ++j) {
    int idx = base + j;
    if (idx < NN) rowptr[idx] = run;
    run += v[j];
  }
  if (t == 255) partial[b] = sd[255];
}

__global__ void scan2_kernel(int* __restrict__ partial) {
  if (threadIdx.x == 0 && blockIdx.x == 0) {
    int run = 0;
    for (int i = 0; i < NB_SCAN; ++i) { int p = partial[i]; partial[i] = run; run += p; }
  }
}

__global__ void scan3_kernel(int* __restrict__ rowptr, const int* __restrict__ partial) {
  int idx = blockIdx.x * 256 + threadIdx.x;
  if (idx < NN) rowptr[idx] += partial[idx >> 10];
}

__global__ void fill_csr_kernel(const int* __restrict__ ei, const int* __restrict__ rowptr,
                                int* __restrict__ cursor, int* __restrict__ csr) {
  int e = blockIdx.x * 256 + threadIdx.x;
  if (e >= ET) return;
  int s, d; edge_sd(e, ei, s, d);
  int pos = atomicAdd(&cursor[d], 1);
  csr[rowptr[d] + pos] = s;
}

// ---------- layer 1: h1 = x @ W1 (fp16 out) + per-head attention dots ----------
// one wave per node (grid-stride). W[:,lane] lives in 128 VGPRs; x row is
// wave-uniform (readfirstlane) -> s_load into SGPRs -> pure v_fmac inner loop.
__global__ __launch_bounds__(256) void gemm1_kernel(
    const float* __restrict__ x, const float* __restrict__ W,
    const float* __restrict__ att_s, const float* __restrict__ att_d,
    __half* __restrict__ h, float* __restrict__ as, float* __restrict__ ad) {
  int lane = threadIdx.x & 63;
  int wid = blockIdx.x * 4 + (threadIdx.x >> 6);
  int nw = gridDim.x * 4;
  float wr[FIN];
#pragma unroll
  for (int k = 0; k < FIN; ++k) wr[k] = W[k * D1 + lane];
  float asv = att_s[lane], adv = att_d[lane];
  for (int node = wid; node < NN; node += nw) {
    int un = __builtin_amdgcn_readfirstlane(node);
    const float* xr = x + (size_t)un * FIN;
    float acc = 0.f;
#pragma unroll
    for (int k = 0; k < FIN; ++k) acc = fmaf(xr[k], wr[k], acc);
    float vs = acc * asv, vd = acc * adv;
#pragma unroll
    for (int off = 1; off < 8; off <<= 1) {
      vs += __shfl_xor(vs, off, 64);
      vd += __shfl_xor(vd, off, 64);
    }
    h[(size_t)node * D1 + lane] = __float2half(acc);
    if ((lane & 7) == 0) {
      as[node * H1 + (lane >> 3)] = vs;
      ad[node * H1 + (lane >> 3)] = vd;
    }
  }
}

// ---------- fused aggregation, layer 1: single pass, no max-shift ----------
__global__ __launch_bounds__(256) void agg1_kernel(
    const int* __restrict__ rowptr, const int* __restrict__ csr,
    const float* __restrict__ as, const float* __restrict__ ad,
    const __half* __restrict__ h, const float* __restrict__ b1,
    float* __restrict__ emb) {
  int node = blockIdx.x * 4 + (threadIdx.x >> 6);
  if (node >= NN) return;
  int lane = threadIdx.x & 63;
  int myh = lane >> 3;
  int beg = rowptr[node];
  int end = (node == NN - 1) ? ET : rowptr[node + 1];
  float adv = ad[node * H1 + myh];
  float den = 0.f, acc = 0.f;
  for (int i = beg; i < end; i += 64) {
    int nch = min(64, end - i);
    int s64 = csr[i + min(lane, nch - 1)];
#pragma unroll 4
    for (int j = 0; j < nch; ++j) {
      int sj = __builtin_amdgcn_readlane(s64, j);  // wave-uniform src id (SGPR)
      float v = as[sj * H1 + myh] + adv;
      v = v >= 0.f ? v : NEG * v;
      float e = __expf(v);
      den += e;
      acc = fmaf(__half2float(h[(long)sj * D1 + lane]), e, acc);
    }
  }
  float o = acc / (den + EPSV) + b1[lane];
  emb[(long)node * D1 + lane] = o > 0.f ? o : expm1f(o);
}

// ---------- layer 2: h2 = emb @ W2 (fp16 out) + attention dots, fused ----------
// one wave per node; lanes 0..39 = class cols. W2[:,col] in 64 VGPRs; emb row
// via uniform s_load; att dots reduced across the wave in the epilogue.
__global__ __launch_bounds__(256) void gemm2_kernel(
    const float* __restrict__ emb, const float* __restrict__ W2,
    const float* __restrict__ att_s, const float* __restrict__ att_d,
    __half* __restrict__ h2, float* __restrict__ as, float* __restrict__ ad) {
  int lane = threadIdx.x & 63;
  int cl = min(lane, C2 - 1);
  int wid = blockIdx.x * 4 + (threadIdx.x >> 6);
  int nw = gridDim.x * 4;
  float w2r[D1];
#pragma unroll
  for (int k = 0; k < D1; ++k) w2r[k] = W2[k * C2 + cl];
  float asv = att_s[cl], adv = att_d[cl];
  for (int node = wid; node < NN; node += nw) {
    int un = __builtin_amdgcn_readfirstlane(node);
    const float* er = emb + (size_t)un * D1;
    float acc = 0.f;
#pragma unroll
    for (int k = 0; k < D1; ++k) acc = fmaf(er[k], w2r[k], acc);
    float hv = (lane < C2) ? acc : 0.f;
    float vs = hv * asv, vd = hv * adv;
#pragma unroll
    for (int off = 1; off < 64; off <<= 1) {
      vs += __shfl_xor(vs, off, 64);
      vd += __shfl_xor(vd, off, 64);
    }
    if (lane < C2) h2[(size_t)node * C2 + lane] = __float2half(acc);
    if (lane == 0) { as[node] = vs; ad[node] = vd; }
  }
}

// ---------- fused aggregation, layer 2 + bias + log_softmax: single pass ----------
__global__ __launch_bounds__(256) void agg2_kernel(
    const int* __restrict__ rowptr, const int* __restrict__ csr,
    const float* __restrict__ as, const float* __restrict__ ad,
    const __half* __restrict__ h2, const float* __restrict__ b2,
    float* __restrict__ out) {
  int node = blockIdx.x * 4 + (threadIdx.x >> 6);
  if (node >= NN) return;
  int lane = threadIdx.x & 63;
  int beg = rowptr[node];
  int end = (node == NN - 1) ? ET : rowptr[node + 1];
  float adv = ad[node];
  float den = 0.f, acc = 0.f;
  for (int i = beg; i < end; i += 64) {
    int nch = min(64, end - i);
    int s64 = csr[i + min(lane, nch - 1)];
#pragma unroll 4
    for (int j = 0; j < nch; ++j) {
      int sj = __builtin_amdgcn_readlane(s64, j);  // wave-uniform src id
      float v = as[sj] + adv;                      // scalar/broadcast load
      v = v >= 0.f ? v : NEG * v;
      float e = __expf(v);
      den += e;
      acc = fmaf(__half2float(h2[(long)sj * C2 + lane]), e, acc);
    }
  }
  // bias + log_softmax over 40 classes
  float val = (lane < C2) ? acc / (den + EPSV) + b2[lane] : -INFINITY;
  float m2 = val;
#pragma unroll
  for (int off = 1; off < 64; off <<= 1) m2 = fmaxf(m2, __shfl_xor(m2, off, 64));
  float ex = (lane < C2) ? __expf(val - m2) : 0.f;
  float sum = ex;
#pragma unroll
  for (int off = 1; off < 64; off <<= 1) sum += __shfl_xor(sum, off, 64);
  if (lane < C2) out[(long)node * C2 + lane] = val - m2 - logf(sum);
}

// ---------- launch ----------
extern "C" void kernel_launch(void* const* d_in, const int* in_sizes, int n_in,
                              void* d_out, int out_size, void* d_ws, size_t ws_size,
                              hipStream_t stream) {
  const float* x    = (const float*)d_in[0];
  const float* W1   = (const float*)d_in[1];
  const float* as1w = (const float*)d_in[2];
  const float* ad1w = (const float*)d_in[3];
  const float* b1   = (const float*)d_in[4];
  const float* W2   = (const float*)d_in[5];
  const float* as2w = (const float*)d_in[6];
  const float* ad2w = (const float*)d_in[7];
  const float* b2   = (const float*)d_in[8];
  const int*   ei   = (const int*)d_in[9];

  float* out   = (float*)d_out;
  float* outls = out;                    // [N,40] log_softmax
  float* emb   = out + (long)NN * C2;    // [N,64] emb

  char* wsb = (char*)d_ws;
  __half* h1   = (__half*)wsb; wsb += sizeof(__half) * (size_t)NN * D1;
  __half* h2   = (__half*)wsb; wsb += sizeof(__half) * ((size_t)NN * C2 + 64);  // +64 pad
  float* asrc1 = (float*)wsb; wsb += sizeof(float) * (size_t)NN * H1;
  float* adst1 = (float*)wsb; wsb += sizeof(float) * (size_t)NN * H1;
  float* asrc2 = (float*)wsb; wsb += sizeof(float) * (size_t)NN;
  float* adst2 = (float*)wsb; wsb += sizeof(float) * (size_t)NN;
  int* deg     = (int*)wsb;   wsb += sizeof(int) * (size_t)NN;
  int* rowptr  = (int*)wsb;   wsb += sizeof(int) * (size_t)NN;
  int* cursor  = (int*)wsb;   wsb += sizeof(int) * (size_t)NN;
  int* partial = (int*)wsb;   wsb += sizeof(int) * 256;
  int* csr     = (int*)wsb;   wsb += sizeof(int) * (size_t)ET;

  // CSR build (per call; ws is re-poisoned each launch)
  hipMemsetAsync(deg, 0, sizeof(int) * (size_t)NN, stream);
  hipMemsetAsync(cursor, 0, sizeof(int) * (size_t)NN, stream);
  int nbE = (ET + 255) / 256;
  deg_kernel<<<nbE, 256, 0, stream>>>(ei, deg);
  scan1_kernel<<<NB_SCAN, 256, 0, stream>>>(deg, rowptr, partial);
  scan2_kernel<<<1, 64, 0, stream>>>(partial);
  scan3_kernel<<<(NN + 255) / 256, 256, 0, stream>>>(rowptr, partial);
  fill_csr_kernel<<<nbE, 256, 0, stream>>>(ei, rowptr, cursor, csr);

  // layer 1
  gemm1_kernel<<<256, 256, 0, stream>>>(x, W1, as1w, ad1w, h1, asrc1, adst1);
  agg1_kernel<<<(NN + 3) / 4, 256, 0, stream>>>(rowptr, csr, asrc1, adst1, h1, b1, emb);

  // layer 2 (gemm + attdot fused)
  gemm2_kernel<<<256, 256, 0, stream>>>(emb, W2, as2w, ad2w, h2, asrc2, adst2);
  agg2_kernel<<<(NN + 3) / 4, 256, 0, stream>>>(rowptr, csr, asrc2, adst2, h2, b2, outls);
}

// Round 6
// 693.360 us; speedup vs baseline: 1.0507x; 1.0507x over previous
//
#include <hip/hip_runtime.h>
#include <hip/hip_fp16.h>
#include <math.h>

#define NN 100000
#define EE 1600000
#define ET (EE + NN)   // 1,700,000 edges incl self-loops
#define FIN 128
#define D1 64          // H1*C1
#define H1 8
#define C1 8
#define C2 40
#define NEG 0.2f
#define EPSV 1e-16f

__device__ __forceinline__ void edge_sd(int e, const int* __restrict__ ei, int& s, int& d) {
  if (e < EE) { s = ei[e]; d = ei[EE + e]; }
  else        { s = e - EE; d = s; }
}

// ---------- CSR build ----------
__global__ void deg_kernel(const int* __restrict__ ei, int* __restrict__ deg) {
  int e = blockIdx.x * 256 + threadIdx.x;
  if (e >= ET) return;
  int s, d; edge_sd(e, ei, s, d);
  atomicAdd(&deg[d], 1);
}

#define NB_SCAN ((NN + 1023) / 1024)
__global__ __launch_bounds__(256) void scan1_kernel(const int* __restrict__ deg,
                                                    int* __restrict__ rowptr,
                                                    int* __restrict__ partial) {
  __shared__ int sd[256];
  int b = blockIdx.x, t = threadIdx.x;
  int base = b * 1024 + t * 4;
  int v[4], s = 0;
#pragma unroll
  for (int j = 0; j < 4; ++j) { int idx = base + j; v[j] = (idx < NN) ? deg[idx] : 0; s += v[j]; }
  sd[t] = s;
  __syncthreads();
  for (int off = 1; off < 256; off <<= 1) {
    int x = sd[t];
    int y = (t >= off) ? sd[t - off] : 0;
    __syncthreads();
    sd[t] = x + y;
    __syncthreads();
  }
  int run = sd[t] - s;
#pragma unroll
  for (int j = 0; j < 4; ++j) {
    int idx = base + j;
    if (idx < NN) rowptr[idx] = run;
    run += v[j];
  }
  if (t == 255) partial[b] = sd[255];
}

__global__ void scan2_kernel(int* __restrict__ partial) {
  if (threadIdx.x == 0 && blockIdx.x == 0) {
    int run = 0;
    for (int i = 0; i < NB_SCAN; ++i) { int p = partial[i]; partial[i] = run; run += p; }
  }
}

__global__ void scan3_kernel(int* __restrict__ rowptr, const int* __restrict__ partial) {
  int idx = blockIdx.x * 256 + threadIdx.x;
  if (idx < NN) rowptr[idx] += partial[idx >> 10];
}

__global__ void fill_csr_kernel(const int* __restrict__ ei, const int* __restrict__ rowptr,
                                int* __restrict__ cursor, int* __restrict__ csr) {
  int e = blockIdx.x * 256 + threadIdx.x;
  if (e >= ET) return;
  int s, d; edge_sd(e, ei, s, d);
  int pos = atomicAdd(&cursor[d], 1);
  csr[rowptr[d] + pos] = s;
}

// ---------- layer 1: h1 = x @ W1 (fp16 out) + per-head attention dots ----------
// W staged in LDS [k][col]; wave handles 8 nodes (lane = col). x rows are
// wave-uniform -> s_load; each LDS W read feeds 8 FMAs.
__global__ __launch_bounds__(256) void gemm1_kernel(
    const float* __restrict__ x, const float* __restrict__ W,
    const float* __restrict__ att_s, const float* __restrict__ att_d,
    __half* __restrict__ h, float* __restrict__ as, float* __restrict__ ad) {
  __shared__ float sW[FIN * D1];   // 32 KB
  int t = threadIdx.x;
  for (int i = t; i < FIN * D1; i += 256) sW[i] = W[i];
  __syncthreads();
  int lane = t & 63;
  int node0 = blockIdx.x * 32 + (t >> 6) * 8;   // wave's first node (uniform)
  int un = __builtin_amdgcn_readfirstlane(node0);
  const float* xb = x + (size_t)un * FIN;
  float asv = att_s[lane], adv = att_d[lane];
  float acc[8];
#pragma unroll
  for (int j = 0; j < 8; ++j) acc[j] = 0.f;
  for (int kk = 0; kk < FIN; kk += 8) {
    float wv[8];
#pragma unroll
    for (int r = 0; r < 8; ++r) wv[r] = sW[(kk + r) * D1 + lane];
#pragma unroll
    for (int j = 0; j < 8; ++j) {
#pragma unroll
      for (int r = 0; r < 8; ++r)
        acc[j] = fmaf(xb[j * FIN + kk + r], wv[r], acc[j]);
    }
  }
#pragma unroll
  for (int j = 0; j < 8; ++j) {
    float vs = acc[j] * asv, vd = acc[j] * adv;
#pragma unroll
    for (int off = 1; off < 8; off <<= 1) {
      vs += __shfl_xor(vs, off, 64);
      vd += __shfl_xor(vd, off, 64);
    }
    int node = node0 + j;
    h[(size_t)node * D1 + lane] = __float2half(acc[j]);
    if ((lane & 7) == 0) {
      as[node * H1 + (lane >> 3)] = vs;
      ad[node * H1 + (lane >> 3)] = vd;
    }
  }
}

// ---------- fused aggregation, layer 1: single pass, no max-shift ----------
__global__ __launch_bounds__(256) void agg1_kernel(
    const int* __restrict__ rowptr, const int* __restrict__ csr,
    const float* __restrict__ as, const float* __restrict__ ad,
    const __half* __restrict__ h, const float* __restrict__ b1,
    float* __restrict__ emb) {
  int node = blockIdx.x * 4 + (threadIdx.x >> 6);
  if (node >= NN) return;
  int lane = threadIdx.x & 63;
  int myh = lane >> 3;
  int beg = rowptr[node];
  int end = (node == NN - 1) ? ET : rowptr[node + 1];
  float adv = ad[node * H1 + myh];
  float den = 0.f, acc = 0.f;
  for (int i = beg; i < end; i += 64) {
    int nch = min(64, end - i);
    int s64 = csr[i + min(lane, nch - 1)];
#pragma unroll 4
    for (int j = 0; j < nch; ++j) {
      int sj = __builtin_amdgcn_readlane(s64, j);  // wave-uniform src id (SGPR)
      float v = as[sj * H1 + myh] + adv;
      v = v >= 0.f ? v : NEG * v;
      float e = __expf(v);
      den += e;
      acc = fmaf(__half2float(h[(long)sj * D1 + lane]), e, acc);
    }
  }
  float o = acc / (den + EPSV) + b1[lane];
  emb[(long)node * D1 + lane] = o > 0.f ? o : expm1f(o);
}

// ---------- layer 2: h2 = emb @ W2 (fp16 out) + attention dots, fused ----------
// W2 zero-padded to 64 cols in LDS; wave handles 8 nodes; emb rows s_loaded.
__global__ __launch_bounds__(256) void gemm2_kernel(
    const float* __restrict__ emb, const float* __restrict__ W2,
    const float* __restrict__ att_s, const float* __restrict__ att_d,
    __half* __restrict__ h2, float* __restrict__ as, float* __restrict__ ad) {
  __shared__ float sW[D1 * D1];   // 16 KB, [k][col] cols 40..63 = 0
  int t = threadIdx.x;
  for (int i = t; i < D1 * D1; i += 256) {
    int k = i >> 6, c = i & 63;
    sW[i] = (c < C2) ? W2[k * C2 + c] : 0.f;
  }
  __syncthreads();
  int lane = t & 63;
  int node0 = blockIdx.x * 32 + (t >> 6) * 8;
  int un = __builtin_amdgcn_readfirstlane(node0);
  const float* eb = emb + (size_t)un * D1;
  float asv = (lane < C2) ? att_s[lane] : 0.f;
  float adv = (lane < C2) ? att_d[lane] : 0.f;
  float acc[8];
#pragma unroll
  for (int j = 0; j < 8; ++j) acc[j] = 0.f;
  for (int kk = 0; kk < D1; kk += 8) {
    float wv[8];
#pragma unroll
    for (int r = 0; r < 8; ++r) wv[r] = sW[(kk + r) * D1 + lane];
#pragma unroll
    for (int j = 0; j < 8; ++j) {
#pragma unroll
      for (int r = 0; r < 8; ++r)
        acc[j] = fmaf(eb[j * D1 + kk + r], wv[r], acc[j]);
    }
  }
#pragma unroll
  for (int j = 0; j < 8; ++j) {
    float vs = acc[j] * asv, vd = acc[j] * adv;
#pragma unroll
    for (int off = 1; off < 64; off <<= 1) {
      vs += __shfl_xor(vs, off, 64);
      vd += __shfl_xor(vd, off, 64);
    }
    int node = node0 + j;
    if (lane < C2) h2[(size_t)node * C2 + lane] = __float2half(acc[j]);
    if (lane == 0) { as[node] = vs; ad[node] = vd; }
  }
}

// ---------- fused aggregation, layer 2 + bias + log_softmax: single pass ----------
__global__ __launch_bounds__(256) void agg2_kernel(
    const int* __restrict__ rowptr, const int* __restrict__ csr,
    const float* __restrict__ as, const float* __restrict__ ad,
    const __half* __restrict__ h2, const float* __restrict__ b2,
    float* __restrict__ out) {
  int node = blockIdx.x * 4 + (threadIdx.x >> 6);
  if (node >= NN) return;
  int lane = threadIdx.x & 63;
  int beg = rowptr[node];
  int end = (node == NN - 1) ? ET : rowptr[node + 1];
  float adv = ad[node];
  float den = 0.f, acc = 0.f;
  for (int i = beg; i < end; i += 64) {
    int nch = min(64, end - i);
    int s64 = csr[i + min(lane, nch - 1)];
#pragma unroll 4
    for (int j = 0; j < nch; ++j) {
      int sj = __builtin_amdgcn_readlane(s64, j);  // wave-uniform src id
      float v = as[sj] + adv;                      // scalar/broadcast load
      v = v >= 0.f ? v : NEG * v;
      float e = __expf(v);
      den += e;
      acc = fmaf(__half2float(h2[(long)sj * C2 + lane]), e, acc);
    }
  }
  // bias + log_softmax over 40 classes
  float val = (lane < C2) ? acc / (den + EPSV) + b2[lane] : -INFINITY;
  float m2 = val;
#pragma unroll
  for (int off = 1; off < 64; off <<= 1) m2 = fmaxf(m2, __shfl_xor(m2, off, 64));
  float ex = (lane < C2) ? __expf(val - m2) : 0.f;
  float sum = ex;
#pragma unroll
  for (int off = 1; off < 64; off <<= 1) sum += __shfl_xor(sum, off, 64);
  if (lane < C2) out[(long)node * C2 + lane] = val - m2 - logf(sum);
}

// ---------- launch ----------
extern "C" void kernel_launch(void* const* d_in, const int* in_sizes, int n_in,
                              void* d_out, int out_size, void* d_ws, size_t ws_size,
                              hipStream_t stream) {
  const float* x    = (const float*)d_in[0];
  const float* W1   = (const float*)d_in[1];
  const float* as1w = (const float*)d_in[2];
  const float* ad1w = (const float*)d_in[3];
  const float* b1   = (const float*)d_in[4];
  const float* W2   = (const float*)d_in[5];
  const float* as2w = (const float*)d_in[6];
  const float* ad2w = (const float*)d_in[7];
  const float* b2   = (const float*)d_in[8];
  const int*   ei   = (const int*)d_in[9];

  float* out   = (float*)d_out;
  float* outls = out;                    // [N,40] log_softmax
  float* emb   = out + (long)NN * C2;    // [N,64] emb

  char* wsb = (char*)d_ws;
  __half* h1   = (__half*)wsb; wsb += sizeof(__half) * (size_t)NN * D1;
  __half* h2   = (__half*)wsb; wsb += sizeof(__half) * ((size_t)NN * C2 + 64);  // +64 pad
  float* asrc1 = (float*)wsb; wsb += sizeof(float) * (size_t)NN * H1;
  float* adst1 = (float*)wsb; wsb += sizeof(float) * (size_t)NN * H1;
  float* asrc2 = (float*)wsb; wsb += sizeof(float) * (size_t)NN;
  float* adst2 = (float*)wsb; wsb += sizeof(float) * (size_t)NN;
  int* deg     = (int*)wsb;   wsb += sizeof(int) * (size_t)NN;
  int* rowptr  = (int*)wsb;   wsb += sizeof(int) * (size_t)NN;
  int* cursor  = (int*)wsb;   wsb += sizeof(int) * (size_t)NN;
  int* partial = (int*)wsb;   wsb += sizeof(int) * 256;
  int* csr     = (int*)wsb;   wsb += sizeof(int) * (size_t)ET;

  // CSR build (per call; ws is re-poisoned each launch)
  hipMemsetAsync(deg, 0, sizeof(int) * (size_t)NN, stream);
  hipMemsetAsync(cursor, 0, sizeof(int) * (size_t)NN, stream);
  int nbE = (ET + 255) / 256;
  deg_kernel<<<nbE, 256, 0, stream>>>(ei, deg);
  scan1_kernel<<<NB_SCAN, 256, 0, stream>>>(deg, rowptr, partial);
  scan2_kernel<<<1, 64, 0, stream>>>(partial);
  scan3_kernel<<<(NN + 255) / 256, 256, 0, stream>>>(rowptr, partial);
  fill_csr_kernel<<<nbE, 256, 0, stream>>>(ei, rowptr, cursor, csr);

  // layer 1  (100000 = 3125 * 32 nodes/block)
  gemm1_kernel<<<3125, 256, 0, stream>>>(x, W1, as1w, ad1w, h1, asrc1, adst1);
  agg1_kernel<<<(NN + 3) / 4, 256, 0, stream>>>(rowptr, csr, asrc1, adst1, h1, b1, emb);

  // layer 2 (gemm + attdot fused)
  gemm2_kernel<<<3125, 256, 0, stream>>>(emb, W2, as2w, ad2w, h2, asrc2, adst2);
  agg2_kernel<<<(NN + 3) / 4, 256, 0, stream>>>(rowptr, csr, asrc2, adst2, h2, b2, outls);
}

// Round 7
// 577.334 us; speedup vs baseline: 1.2618x; 1.2010x over previous
//
#include <hip/hip_runtime.h>
#include <hip/hip_fp16.h>
#include <math.h>

#define NN 100000
#define EE 1600000
#define ET (EE + NN)   // 1,700,000 edges incl self-loops
#define FIN 128
#define D1 64          // H1*C1
#define H1 8
#define C1 8
#define C2 40
#define NEG 0.2f
#define EPSV 1e-16f

__device__ __forceinline__ void edge_sd(int e, const int* __restrict__ ei, int& s, int& d) {
  if (e < EE) { s = ei[e]; d = ei[EE + e]; }
  else        { s = e - EE; d = s; }
}

// ---------- CSR build ----------
__global__ void deg_kernel(const int* __restrict__ ei, int* __restrict__ deg) {
  int e = blockIdx.x * 256 + threadIdx.x;
  if (e >= ET) return;
  int s, d; edge_sd(e, ei, s, d);
  atomicAdd(&deg[d], 1);
}

#define NB_SCAN ((NN + 1023) / 1024)
__global__ __launch_bounds__(256) void scan1_kernel(const int* __restrict__ deg,
                                                    int* __restrict__ rowptr,
                                                    int* __restrict__ partial) {
  __shared__ int sd[256];
  int b = blockIdx.x, t = threadIdx.x;
  int base = b * 1024 + t * 4;
  int v[4], s = 0;
#pragma unroll
  for (int j = 0; j < 4; ++j) { int idx = base + j; v[j] = (idx < NN) ? deg[idx] : 0; s += v[j]; }
  sd[t] = s;
  __syncthreads();
  for (int off = 1; off < 256; off <<= 1) {
    int x = sd[t];
    int y = (t >= off) ? sd[t - off] : 0;
    __syncthreads();
    sd[t] = x + y;
    __syncthreads();
  }
  int run = sd[t] - s;
#pragma unroll
  for (int j = 0; j < 4; ++j) {
    int idx = base + j;
    if (idx < NN) rowptr[idx] = run;
    run += v[j];
  }
  if (t == 255) partial[b] = sd[255];
}

__global__ void scan2_kernel(int* __restrict__ partial) {
  if (threadIdx.x == 0 && blockIdx.x == 0) {
    int run = 0;
    for (int i = 0; i < NB_SCAN; ++i) { int p = partial[i]; partial[i] = run; run += p; }
  }
}

__global__ void scan3_kernel(int* __restrict__ rowptr, const int* __restrict__ partial) {
  int idx = blockIdx.x * 256 + threadIdx.x;
  if (idx < NN) rowptr[idx] += partial[idx >> 10];
}

__global__ void fill_csr_kernel(const int* __restrict__ ei, const int* __restrict__ rowptr,
                                int* __restrict__ cursor, int* __restrict__ csr) {
  int e = blockIdx.x * 256 + threadIdx.x;
  if (e >= ET) return;
  int s, d; edge_sd(e, ei, s, d);
  int pos = atomicAdd(&cursor[d], 1);
  csr[rowptr[d] + pos] = s;
}

// ---------- layer 1: tiled GEMM 64 nodes x 64 cols, K=128, + att dots ----------
// thread = 4 nodes x 4 cols. lane: ng = lane&15 (node group), cgl = lane>>4.
// cols = wid*16 + cgl*4 .. +3. x tile swizzled so compute reads are ~conflict-free.
__global__ __launch_bounds__(256) void gemm1_kernel(
    const float* __restrict__ x, const float* __restrict__ W,
    const float* __restrict__ att_s, const float* __restrict__ att_d,
    __half* __restrict__ h, float* __restrict__ as, float* __restrict__ ad) {
  __shared__ float sW[FIN * D1];   // [k][col], 32 KB
  __shared__ float sx[64 * FIN];   // swizzled, 32 KB
  int t = threadIdx.x;
  int node0 = blockIdx.x * 64;
  {
    const float4* Wg = (const float4*)W;
    float4* sWq = (float4*)sW;
    for (int i = t; i < FIN * D1 / 4; i += 256) sWq[i] = Wg[i];
  }
  for (int idx = t; idx < 64 * 32; idx += 256) {
    int node = idx >> 5, kq = idx & 31;
    float4 v = make_float4(0.f, 0.f, 0.f, 0.f);
    if (node0 + node < NN) v = ((const float4*)x)[(size_t)(node0 + node) * 32 + kq];
    *(float4*)&sx[node * FIN + ((kq * 4 + 4 * (node >> 2)) & 127)] = v;
  }
  __syncthreads();
  int lane = t & 63, wid = t >> 6;
  int ng = lane & 15, cgl = lane >> 4;
  int col0 = wid * 16 + cgl * 4;
  float acc[4][4];
#pragma unroll
  for (int a = 0; a < 4; ++a)
#pragma unroll
    for (int c = 0; c < 4; ++c) acc[a][c] = 0.f;
  for (int kk = 0; kk < FIN; kk += 4) {
    float4 xv[4], wv[4];
#pragma unroll
    for (int a = 0; a < 4; ++a) {
      int node = ng * 4 + a;
      xv[a] = *(const float4*)&sx[node * FIN + ((kk + 4 * (node >> 2)) & 127)];
    }
#pragma unroll
    for (int b = 0; b < 4; ++b) wv[b] = *(const float4*)&sW[(kk + b) * D1 + col0];
#pragma unroll
    for (int a = 0; a < 4; ++a) {
      acc[a][0] = fmaf(xv[a].x, wv[0].x, acc[a][0]);
      acc[a][1] = fmaf(xv[a].x, wv[0].y, acc[a][1]);
      acc[a][2] = fmaf(xv[a].x, wv[0].z, acc[a][2]);
      acc[a][3] = fmaf(xv[a].x, wv[0].w, acc[a][3]);
      acc[a][0] = fmaf(xv[a].y, wv[1].x, acc[a][0]);
      acc[a][1] = fmaf(xv[a].y, wv[1].y, acc[a][1]);
      acc[a][2] = fmaf(xv[a].y, wv[1].z, acc[a][2]);
      acc[a][3] = fmaf(xv[a].y, wv[1].w, acc[a][3]);
      acc[a][0] = fmaf(xv[a].z, wv[2].x, acc[a][0]);
      acc[a][1] = fmaf(xv[a].z, wv[2].y, acc[a][1]);
      acc[a][2] = fmaf(xv[a].z, wv[2].z, acc[a][2]);
      acc[a][3] = fmaf(xv[a].z, wv[2].w, acc[a][3]);
      acc[a][0] = fmaf(xv[a].w, wv[3].x, acc[a][0]);
      acc[a][1] = fmaf(xv[a].w, wv[3].y, acc[a][1]);
      acc[a][2] = fmaf(xv[a].w, wv[3].z, acc[a][2]);
      acc[a][3] = fmaf(xv[a].w, wv[3].w, acc[a][3]);
    }
  }
  // h writes (fp16, 8B per node)
#pragma unroll
  for (int a = 0; a < 4; ++a) {
    int node = node0 + ng * 4 + a;
    if (node < NN) {
      __half2 p01 = __floats2half2_rn(acc[a][0], acc[a][1]);
      __half2 p23 = __floats2half2_rn(acc[a][2], acc[a][3]);
      __half2* hp = (__half2*)&h[(size_t)node * D1 + col0];
      hp[0] = p01; hp[1] = p23;
    }
  }
  // att dots: head = 2*wid + (cgl>>1); cgl pairs combined via shfl_xor(16)
  float aw_s[4], aw_d[4];
#pragma unroll
  for (int j = 0; j < 4; ++j) { aw_s[j] = att_s[col0 + j]; aw_d[j] = att_d[col0 + j]; }
#pragma unroll
  for (int a = 0; a < 4; ++a) {
    float ps = acc[a][0]*aw_s[0] + acc[a][1]*aw_s[1] + acc[a][2]*aw_s[2] + acc[a][3]*aw_s[3];
    float pd = acc[a][0]*aw_d[0] + acc[a][1]*aw_d[1] + acc[a][2]*aw_d[2] + acc[a][3]*aw_d[3];
    ps += __shfl_xor(ps, 16, 64);
    pd += __shfl_xor(pd, 16, 64);
    int node = node0 + ng * 4 + a;
    if ((cgl & 1) == 0 && node < NN) {
      int head = 2 * wid + (cgl >> 1);
      as[node * H1 + head] = ps;
      ad[node * H1 + head] = pd;
    }
  }
}

// ---------- fused aggregation, layer 1: single pass, no max-shift ----------
__global__ __launch_bounds__(256) void agg1_kernel(
    const int* __restrict__ rowptr, const int* __restrict__ csr,
    const float* __restrict__ as, const float* __restrict__ ad,
    const __half* __restrict__ h, const float* __restrict__ b1,
    float* __restrict__ emb) {
  int node = blockIdx.x * 4 + (threadIdx.x >> 6);
  if (node >= NN) return;
  int lane = threadIdx.x & 63;
  int myh = lane >> 3;
  int beg = rowptr[node];
  int end = (node == NN - 1) ? ET : rowptr[node + 1];
  float adv = ad[node * H1 + myh];
  float den = 0.f, acc = 0.f;
  for (int i = beg; i < end; i += 64) {
    int nch = min(64, end - i);
    int s64 = csr[i + min(lane, nch - 1)];
#pragma unroll 4
    for (int j = 0; j < nch; ++j) {
      int sj = __builtin_amdgcn_readlane(s64, j);  // wave-uniform src id (SGPR)
      float v = as[sj * H1 + myh] + adv;
      v = v >= 0.f ? v : NEG * v;
      float e = __expf(v);
      den += e;
      acc = fmaf(__half2float(h[(long)sj * D1 + lane]), e, acc);
    }
  }
  float o = acc / (den + EPSV) + b1[lane];
  emb[(long)node * D1 + lane] = o > 0.f ? o : expm1f(o);
}

// ---------- layer 2: tiled GEMM 64 nodes x 64 cols (40 real), K=64, + att dots ----------
__global__ __launch_bounds__(256) void gemm2_kernel(
    const float* __restrict__ emb, const float* __restrict__ W2,
    const float* __restrict__ att_s, const float* __restrict__ att_d,
    __half* __restrict__ h2, float* __restrict__ as, float* __restrict__ ad) {
  __shared__ float sW[D1 * D1];    // [k][col64], cols>=40 zero, 16 KB
  __shared__ float se[64 * D1];    // swizzled, 16 KB
  __shared__ float sred_s[64], sred_d[64];
  int t = threadIdx.x;
  int node0 = blockIdx.x * 64;
  for (int i = t; i < D1 * D1; i += 256) {
    int k = i >> 6, c = i & 63;
    sW[i] = (c < C2) ? W2[k * C2 + c] : 0.f;
  }
  for (int idx = t; idx < 64 * 16; idx += 256) {
    int node = idx >> 4, kq = idx & 15;
    float4 v = make_float4(0.f, 0.f, 0.f, 0.f);
    if (node0 + node < NN) v = ((const float4*)emb)[(size_t)(node0 + node) * 16 + kq];
    *(float4*)&se[node * D1 + ((kq * 4 + 4 * (node >> 2)) & 63)] = v;
  }
  if (t < 64) { sred_s[t] = 0.f; sred_d[t] = 0.f; }
  __syncthreads();
  int lane = t & 63, wid = t >> 6;
  int ng = lane & 15, cgl = lane >> 4;
  int col0 = wid * 16 + cgl * 4;
  float acc[4][4];
#pragma unroll
  for (int a = 0; a < 4; ++a)
#pragma unroll
    for (int c = 0; c < 4; ++c) acc[a][c] = 0.f;
  for (int kk = 0; kk < D1; kk += 4) {
    float4 xv[4], wv[4];
#pragma unroll
    for (int a = 0; a < 4; ++a) {
      int node = ng * 4 + a;
      xv[a] = *(const float4*)&se[node * D1 + ((kk + 4 * (node >> 2)) & 63)];
    }
#pragma unroll
    for (int b = 0; b < 4; ++b) wv[b] = *(const float4*)&sW[(kk + b) * D1 + col0];
#pragma unroll
    for (int a = 0; a < 4; ++a) {
      acc[a][0] = fmaf(xv[a].x, wv[0].x, acc[a][0]);
      acc[a][1] = fmaf(xv[a].x, wv[0].y, acc[a][1]);
      acc[a][2] = fmaf(xv[a].x, wv[0].z, acc[a][2]);
      acc[a][3] = fmaf(xv[a].x, wv[0].w, acc[a][3]);
      acc[a][0] = fmaf(xv[a].y, wv[1].x, acc[a][0]);
      acc[a][1] = fmaf(xv[a].y, wv[1].y, acc[a][1]);
      acc[a][2] = fmaf(xv[a].y, wv[1].z, acc[a][2]);
      acc[a][3] = fmaf(xv[a].y, wv[1].w, acc[a][3]);
      acc[a][0] = fmaf(xv[a].z, wv[2].x, acc[a][0]);
      acc[a][1] = fmaf(xv[a].z, wv[2].y, acc[a][1]);
      acc[a][2] = fmaf(xv[a].z, wv[2].z, acc[a][2]);
      acc[a][3] = fmaf(xv[a].z, wv[2].w, acc[a][3]);
      acc[a][0] = fmaf(xv[a].w, wv[3].x, acc[a][0]);
      acc[a][1] = fmaf(xv[a].w, wv[3].y, acc[a][1]);
      acc[a][2] = fmaf(xv[a].w, wv[3].z, acc[a][2]);
      acc[a][3] = fmaf(xv[a].w, wv[3].w, acc[a][3]);
    }
  }
  if (col0 < C2) {  // col0 in {0,...,36}: all 4 cols < 40
#pragma unroll
    for (int a = 0; a < 4; ++a) {
      int node = node0 + ng * 4 + a;
      if (node < NN) {
        __half2 p01 = __floats2half2_rn(acc[a][0], acc[a][1]);
        __half2 p23 = __floats2half2_rn(acc[a][2], acc[a][3]);
        __half2* hp = (__half2*)&h2[(size_t)node * C2 + col0];
        hp[0] = p01; hp[1] = p23;
      }
    }
    float aw_s[4], aw_d[4];
#pragma unroll
    for (int j = 0; j < 4; ++j) { aw_s[j] = att_s[col0 + j]; aw_d[j] = att_d[col0 + j]; }
#pragma unroll
    for (int a = 0; a < 4; ++a) {
      float ps = acc[a][0]*aw_s[0] + acc[a][1]*aw_s[1] + acc[a][2]*aw_s[2] + acc[a][3]*aw_s[3];
      float pd = acc[a][0]*aw_d[0] + acc[a][1]*aw_d[1] + acc[a][2]*aw_d[2] + acc[a][3]*aw_d[3];
      atomicAdd(&sred_s[ng * 4 + a], ps);
      atomicAdd(&sred_d[ng * 4 + a], pd);
    }
  }
  __syncthreads();
  if (t < 64 && node0 + t < NN) { as[node0 + t] = sred_s[t]; ad[node0 + t] = sred_d[t]; }
}

// ---------- fused aggregation, layer 2 + bias + log_softmax: single pass ----------
__global__ __launch_bounds__(256) void agg2_kernel(
    const int* __restrict__ rowptr, const int* __restrict__ csr,
    const float* __restrict__ as, const float* __restrict__ ad,
    const __half* __restrict__ h2, const float* __restrict__ b2,
    float* __restrict__ out) {
  int node = blockIdx.x * 4 + (threadIdx.x >> 6);
  if (node >= NN) return;
  int lane = threadIdx.x & 63;
  int beg = rowptr[node];
  int end = (node == NN - 1) ? ET : rowptr[node + 1];
  float adv = ad[node];
  float den = 0.f, acc = 0.f;
  for (int i = beg; i < end; i += 64) {
    int nch = min(64, end - i);
    int s64 = csr[i + min(lane, nch - 1)];
#pragma unroll 4
    for (int j = 0; j < nch; ++j) {
      int sj = __builtin_amdgcn_readlane(s64, j);  // wave-uniform src id
      float v = as[sj] + adv;                      // scalar/broadcast load
      v = v >= 0.f ? v : NEG * v;
      float e = __expf(v);
      den += e;
      acc = fmaf(__half2float(h2[(long)sj * C2 + lane]), e, acc);
    }
  }
  // bias + log_softmax over 40 classes
  float val = (lane < C2) ? acc / (den + EPSV) + b2[lane] : -INFINITY;
  float m2 = val;
#pragma unroll
  for (int off = 1; off < 64; off <<= 1) m2 = fmaxf(m2, __shfl_xor(m2, off, 64));
  float ex = (lane < C2) ? __expf(val - m2) : 0.f;
  float sum = ex;
#pragma unroll
  for (int off = 1; off < 64; off <<= 1) sum += __shfl_xor(sum, off, 64);
  if (lane < C2) out[(long)node * C2 + lane] = val - m2 - logf(sum);
}

// ---------- launch ----------
extern "C" void kernel_launch(void* const* d_in, const int* in_sizes, int n_in,
                              void* d_out, int out_size, void* d_ws, size_t ws_size,
                              hipStream_t stream) {
  const float* x    = (const float*)d_in[0];
  const float* W1   = (const float*)d_in[1];
  const float* as1w = (const float*)d_in[2];
  const float* ad1w = (const float*)d_in[3];
  const float* b1   = (const float*)d_in[4];
  const float* W2   = (const float*)d_in[5];
  const float* as2w = (const float*)d_in[6];
  const float* ad2w = (const float*)d_in[7];
  const float* b2   = (const float*)d_in[8];
  const int*   ei   = (const int*)d_in[9];

  float* out   = (float*)d_out;
  float* outls = out;                    // [N,40] log_softmax
  float* emb   = out + (long)NN * C2;    // [N,64] emb

  char* wsb = (char*)d_ws;
  __half* h1   = (__half*)wsb; wsb += sizeof(__half) * (size_t)NN * D1;
  __half* h2   = (__half*)wsb; wsb += sizeof(__half) * ((size_t)NN * C2 + 64);  // +64 pad
  float* asrc1 = (float*)wsb; wsb += sizeof(float) * (size_t)NN * H1;
  float* adst1 = (float*)wsb; wsb += sizeof(float) * (size_t)NN * H1;
  float* asrc2 = (float*)wsb; wsb += sizeof(float) * (size_t)NN;
  float* adst2 = (float*)wsb; wsb += sizeof(float) * (size_t)NN;
  int* deg     = (int*)wsb;   wsb += sizeof(int) * (size_t)NN;
  int* rowptr  = (int*)wsb;   wsb += sizeof(int) * (size_t)NN;
  int* cursor  = (int*)wsb;   wsb += sizeof(int) * (size_t)NN;
  int* partial = (int*)wsb;   wsb += sizeof(int) * 256;
  int* csr     = (int*)wsb;   wsb += sizeof(int) * (size_t)ET;

  // CSR build (per call; ws is re-poisoned each launch)
  hipMemsetAsync(deg, 0, sizeof(int) * (size_t)NN, stream);
  hipMemsetAsync(cursor, 0, sizeof(int) * (size_t)NN, stream);
  int nbE = (ET + 255) / 256;
  deg_kernel<<<nbE, 256, 0, stream>>>(ei, deg);
  scan1_kernel<<<NB_SCAN, 256, 0, stream>>>(deg, rowptr, partial);
  scan2_kernel<<<1, 64, 0, stream>>>(partial);
  scan3_kernel<<<(NN + 255) / 256, 256, 0, stream>>>(rowptr, partial);
  fill_csr_kernel<<<nbE, 256, 0, stream>>>(ei, rowptr, cursor, csr);

  // layer 1
  gemm1_kernel<<<(NN + 63) / 64, 256, 0, stream>>>(x, W1, as1w, ad1w, h1, asrc1, adst1);
  agg1_kernel<<<(NN + 3) / 4, 256, 0, stream>>>(rowptr, csr, asrc1, adst1, h1, b1, emb);

  // layer 2 (gemm + attdot fused)
  gemm2_kernel<<<(NN + 63) / 64, 256, 0, stream>>>(emb, W2, as2w, ad2w, h2, asrc2, adst2);
  agg2_kernel<<<(NN + 3) / 4, 256, 0, stream>>>(rowptr, csr, asrc2, adst2, h2, b2, outls);
}

// Round 8
// 388.562 us; speedup vs baseline: 1.8749x; 1.4858x over previous
//
#include <hip/hip_runtime.h>
#include <hip/hip_fp16.h>
#include <math.h>

#define NN 100000
#define EE 1600000
#define ET (EE + NN)   // 1,700,000 edges incl self-loops
#define FIN 128
#define D1 64          // H1*C1
#define H1 8
#define C1 8
#define C2 40
#define NEG 0.2f
#define EPSV 1e-16f

#define NBKT 196       // buckets of 512 dst: (99999>>9)+1
#define CHUNK 8192     // edges per scatter block
#define NBB ((ET + CHUNK - 1) / CHUNK)

__device__ __forceinline__ void edge_sd(int e, const int* __restrict__ ei, int& s, int& d) {
  if (e < EE) { s = ei[e]; d = ei[EE + e]; }
  else        { s = e - EE; d = s; }
}

// ---------- CSR build: bucket histogram ----------
__global__ __launch_bounds__(256) void hist_kernel(const int* __restrict__ ei,
                                                   int* __restrict__ ghist) {
  __shared__ int lh[NBKT];
  int t = threadIdx.x;
  if (t < NBKT) lh[t] = 0;
  __syncthreads();
  for (int e = blockIdx.x * 256 + t; e < ET; e += gridDim.x * 256) {
    int d = (e < EE) ? ei[EE + e] : e - EE;
    atomicAdd(&lh[d >> 9], 1);
  }
  __syncthreads();
  if (t < NBKT && lh[t]) atomicAdd(&ghist[t], lh[t]);
}

__global__ __launch_bounds__(256) void bscan_kernel(const int* __restrict__ ghist,
                                                    int* __restrict__ bbase) {
  __shared__ int sd[256];
  int t = threadIdx.x;
  int v = (t < NBKT) ? ghist[t] : 0;
  sd[t] = v;
  __syncthreads();
  for (int off = 1; off < 256; off <<= 1) {
    int x = sd[t];
    int y = (t >= off) ? sd[t - off] : 0;
    __syncthreads();
    sd[t] = x + y;
    __syncthreads();
  }
  int excl = sd[t] - v;
  if (t < NBKT) bbase[t] = excl;
  if (t == NBKT - 1) bbase[NBKT] = excl + v;
}

// ---------- scatter edges into bucket array (run-reserved, write-local) ----------
__global__ __launch_bounds__(256) void scatter_kernel(const int* __restrict__ ei,
                                                      const int* __restrict__ bbase,
                                                      int* __restrict__ gcur,
                                                      int* __restrict__ barr) {
  __shared__ int lh[NBKT], lres[NBKT], lcur[NBKT];
  int t = threadIdx.x;
  if (t < NBKT) { lh[t] = 0; lcur[t] = 0; }
  __syncthreads();
  int e0 = blockIdx.x * CHUNK;
  int e1 = min(e0 + CHUNK, ET);
  for (int e = e0 + t; e < e1; e += 256) {
    int d = (e < EE) ? ei[EE + e] : e - EE;
    atomicAdd(&lh[d >> 9], 1);
  }
  __syncthreads();
  if (t < NBKT && lh[t]) lres[t] = atomicAdd(&gcur[t], lh[t]);
  __syncthreads();
  for (int e = e0 + t; e < e1; e += 256) {
    int s, d; edge_sd(e, ei, s, d);
    int b = d >> 9;
    int lp = atomicAdd(&lcur[b], 1);
    barr[bbase[b] + lres[b] + lp] = s | ((d & 511) << 17);
  }
}

// ---------- per-bucket: local hist+scan -> rowptr + csr (L2-local writes) ----------
__global__ __launch_bounds__(256) void bucket2csr_kernel(const int* __restrict__ barr,
                                                         const int* __restrict__ bbase,
                                                         int* __restrict__ rowptr,
                                                         int* __restrict__ csr) {
  __shared__ int hist[512];
  __shared__ int sd[256];
  int b = blockIdx.x, t = threadIdx.x;
  int base = bbase[b];
  int cnt = bbase[b + 1] - base;
  hist[t] = 0; hist[t + 256] = 0;
  __syncthreads();
  for (int i = t; i < cnt; i += 256) atomicAdd(&hist[barr[base + i] >> 17], 1);
  __syncthreads();
  int h0 = hist[2 * t], h1 = hist[2 * t + 1], s = h0 + h1;
  sd[t] = s;
  __syncthreads();
  for (int off = 1; off < 256; off <<= 1) {
    int x = sd[t];
    int y = (t >= off) ? sd[t - off] : 0;
    __syncthreads();
    sd[t] = x + y;
    __syncthreads();
  }
  int run = sd[t] - s;   // exclusive base for local dst 2t
  int g = b * 512 + 2 * t;
  if (g < NN) rowptr[g] = base + run;
  if (g + 1 < NN) rowptr[g + 1] = base + run + h0;
  hist[2 * t] = run;
  hist[2 * t + 1] = run + h0;
  __syncthreads();
  for (int i = t; i < cnt; i += 256) {
    int p = barr[base + i];
    int dl = p >> 17;
    int pos = atomicAdd(&hist[dl], 1);
    csr[base + pos] = p & 0x1FFFF;
  }
}

// ---------- layer 1: tiled GEMM 64 nodes x 64 cols, K=128, + att dots ----------
__global__ __launch_bounds__(256) void gemm1_kernel(
    const float* __restrict__ x, const float* __restrict__ W,
    const float* __restrict__ att_s, const float* __restrict__ att_d,
    __half* __restrict__ h, float* __restrict__ as, float* __restrict__ ad) {
  __shared__ float sW[FIN * D1];   // [k][col], 32 KB
  __shared__ float sx[64 * FIN];   // swizzled, 32 KB
  int t = threadIdx.x;
  int node0 = blockIdx.x * 64;
  {
    const float4* Wg = (const float4*)W;
    float4* sWq = (float4*)sW;
    for (int i = t; i < FIN * D1 / 4; i += 256) sWq[i] = Wg[i];
  }
  for (int idx = t; idx < 64 * 32; idx += 256) {
    int node = idx >> 5, kq = idx & 31;
    float4 v = make_float4(0.f, 0.f, 0.f, 0.f);
    if (node0 + node < NN) v = ((const float4*)x)[(size_t)(node0 + node) * 32 + kq];
    *(float4*)&sx[node * FIN + ((kq * 4 + 4 * (node >> 2)) & 127)] = v;
  }
  __syncthreads();
  int lane = t & 63, wid = t >> 6;
  int ng = lane & 15, cgl = lane >> 4;
  int col0 = wid * 16 + cgl * 4;
  float acc[4][4];
#pragma unroll
  for (int a = 0; a < 4; ++a)
#pragma unroll
    for (int c = 0; c < 4; ++c) acc[a][c] = 0.f;
  for (int kk = 0; kk < FIN; kk += 4) {
    float4 xv[4], wv[4];
#pragma unroll
    for (int a = 0; a < 4; ++a) {
      int node = ng * 4 + a;
      xv[a] = *(const float4*)&sx[node * FIN + ((kk + 4 * (node >> 2)) & 127)];
    }
#pragma unroll
    for (int b = 0; b < 4; ++b) wv[b] = *(const float4*)&sW[(kk + b) * D1 + col0];
#pragma unroll
    for (int a = 0; a < 4; ++a) {
      acc[a][0] = fmaf(xv[a].x, wv[0].x, acc[a][0]);
      acc[a][1] = fmaf(xv[a].x, wv[0].y, acc[a][1]);
      acc[a][2] = fmaf(xv[a].x, wv[0].z, acc[a][2]);
      acc[a][3] = fmaf(xv[a].x, wv[0].w, acc[a][3]);
      acc[a][0] = fmaf(xv[a].y, wv[1].x, acc[a][0]);
      acc[a][1] = fmaf(xv[a].y, wv[1].y, acc[a][1]);
      acc[a][2] = fmaf(xv[a].y, wv[1].z, acc[a][2]);
      acc[a][3] = fmaf(xv[a].y, wv[1].w, acc[a][3]);
      acc[a][0] = fmaf(xv[a].z, wv[2].x, acc[a][0]);
      acc[a][1] = fmaf(xv[a].z, wv[2].y, acc[a][1]);
      acc[a][2] = fmaf(xv[a].z, wv[2].z, acc[a][2]);
      acc[a][3] = fmaf(xv[a].z, wv[2].w, acc[a][3]);
      acc[a][0] = fmaf(xv[a].w, wv[3].x, acc[a][0]);
      acc[a][1] = fmaf(xv[a].w, wv[3].y, acc[a][1]);
      acc[a][2] = fmaf(xv[a].w, wv[3].z, acc[a][2]);
      acc[a][3] = fmaf(xv[a].w, wv[3].w, acc[a][3]);
    }
  }
#pragma unroll
  for (int a = 0; a < 4; ++a) {
    int node = node0 + ng * 4 + a;
    if (node < NN) {
      __half2 p01 = __floats2half2_rn(acc[a][0], acc[a][1]);
      __half2 p23 = __floats2half2_rn(acc[a][2], acc[a][3]);
      __half2* hp = (__half2*)&h[(size_t)node * D1 + col0];
      hp[0] = p01; hp[1] = p23;
    }
  }
  float aw_s[4], aw_d[4];
#pragma unroll
  for (int j = 0; j < 4; ++j) { aw_s[j] = att_s[col0 + j]; aw_d[j] = att_d[col0 + j]; }
#pragma unroll
  for (int a = 0; a < 4; ++a) {
    float ps = acc[a][0]*aw_s[0] + acc[a][1]*aw_s[1] + acc[a][2]*aw_s[2] + acc[a][3]*aw_s[3];
    float pd = acc[a][0]*aw_d[0] + acc[a][1]*aw_d[1] + acc[a][2]*aw_d[2] + acc[a][3]*aw_d[3];
    ps += __shfl_xor(ps, 16, 64);
    pd += __shfl_xor(pd, 16, 64);
    int node = node0 + ng * 4 + a;
    if ((cgl & 1) == 0 && node < NN) {
      int head = 2 * wid + (cgl >> 1);
      as[node * H1 + head] = ps;
      ad[node * H1 + head] = pd;
    }
  }
}

// ---------- fused aggregation, layer 1: single pass, batched-8 edges ----------
__global__ __launch_bounds__(256) void agg1_kernel(
    const int* __restrict__ rowptr, const int* __restrict__ csr,
    const float* __restrict__ as, const float* __restrict__ ad,
    const __half* __restrict__ h, const float* __restrict__ b1,
    float* __restrict__ emb) {
  int node = blockIdx.x * 4 + (threadIdx.x >> 6);
  if (node >= NN) return;
  int lane = threadIdx.x & 63;
  int myh = lane >> 3;
  int beg = rowptr[node];
  int end = (node == NN - 1) ? ET : rowptr[node + 1];
  float adv = ad[node * H1 + myh];
  float den = 0.f, acc = 0.f;
  for (int i = beg; i < end; i += 64) {
    int nch = min(64, end - i);
    int s64 = csr[i + min(lane, nch - 1)];
    int j = 0;
    for (; j + 8 <= nch; j += 8) {
      const __half* hr[8]; const float* ar[8];
      float hv[8], ev[8];
#pragma unroll
      for (int r = 0; r < 8; ++r) {
        int sj = __builtin_amdgcn_readlane(s64, j + r);
        hr[r] = h + (size_t)sj * D1;
        ar[r] = as + sj * H1;
      }
#pragma unroll
      for (int r = 0; r < 8; ++r) hv[r] = __half2float(hr[r][lane]);
#pragma unroll
      for (int r = 0; r < 8; ++r) {
        float v = ar[r][myh] + adv;
        v = fmaxf(v, NEG * v);
        ev[r] = __expf(v);
      }
#pragma unroll
      for (int r = 0; r < 8; ++r) { den += ev[r]; acc = fmaf(hv[r], ev[r], acc); }
    }
    for (; j < nch; ++j) {
      int sj = __builtin_amdgcn_readlane(s64, j);
      float v = as[sj * H1 + myh] + adv;
      v = fmaxf(v, NEG * v);
      float e = __expf(v);
      den += e;
      acc = fmaf(__half2float(h[(size_t)sj * D1 + lane]), e, acc);
    }
  }
  float o = acc / (den + EPSV) + b1[lane];
  emb[(size_t)node * D1 + lane] = o > 0.f ? o : expm1f(o);
}

// ---------- layer 2: tiled GEMM 64 nodes x 64 cols (40 real), K=64, + att dots ----------
__global__ __launch_bounds__(256) void gemm2_kernel(
    const float* __restrict__ emb, const float* __restrict__ W2,
    const float* __restrict__ att_s, const float* __restrict__ att_d,
    __half* __restrict__ h2, float* __restrict__ as, float* __restrict__ ad) {
  __shared__ float sW[D1 * D1];    // [k][col64], cols>=40 zero, 16 KB
  __shared__ float se[64 * D1];    // swizzled, 16 KB
  __shared__ float sred_s[64], sred_d[64];
  int t = threadIdx.x;
  int node0 = blockIdx.x * 64;
  for (int i = t; i < D1 * D1; i += 256) {
    int k = i >> 6, c = i & 63;
    sW[i] = (c < C2) ? W2[k * C2 + c] : 0.f;
  }
  for (int idx = t; idx < 64 * 16; idx += 256) {
    int node = idx >> 4, kq = idx & 15;
    float4 v = make_float4(0.f, 0.f, 0.f, 0.f);
    if (node0 + node < NN) v = ((const float4*)emb)[(size_t)(node0 + node) * 16 + kq];
    *(float4*)&se[node * D1 + ((kq * 4 + 4 * (node >> 2)) & 63)] = v;
  }
  if (t < 64) { sred_s[t] = 0.f; sred_d[t] = 0.f; }
  __syncthreads();
  int lane = t & 63, wid = t >> 6;
  int ng = lane & 15, cgl = lane >> 4;
  int col0 = wid * 16 + cgl * 4;
  float acc[4][4];
#pragma unroll
  for (int a = 0; a < 4; ++a)
#pragma unroll
    for (int c = 0; c < 4; ++c) acc[a][c] = 0.f;
  for (int kk = 0; kk < D1; kk += 4) {
    float4 xv[4], wv[4];
#pragma unroll
    for (int a = 0; a < 4; ++a) {
      int node = ng * 4 + a;
      xv[a] = *(const float4*)&se[node * D1 + ((kk + 4 * (node >> 2)) & 63)];
    }
#pragma unroll
    for (int b = 0; b < 4; ++b) wv[b] = *(const float4*)&sW[(kk + b) * D1 + col0];
#pragma unroll
    for (int a = 0; a < 4; ++a) {
      acc[a][0] = fmaf(xv[a].x, wv[0].x, acc[a][0]);
      acc[a][1] = fmaf(xv[a].x, wv[0].y, acc[a][1]);
      acc[a][2] = fmaf(xv[a].x, wv[0].z, acc[a][2]);
      acc[a][3] = fmaf(xv[a].x, wv[0].w, acc[a][3]);
      acc[a][0] = fmaf(xv[a].y, wv[1].x, acc[a][0]);
      acc[a][1] = fmaf(xv[a].y, wv[1].y, acc[a][1]);
      acc[a][2] = fmaf(xv[a].y, wv[1].z, acc[a][2]);
      acc[a][3] = fmaf(xv[a].y, wv[1].w, acc[a][3]);
      acc[a][0] = fmaf(xv[a].z, wv[2].x, acc[a][0]);
      acc[a][1] = fmaf(xv[a].z, wv[2].y, acc[a][1]);
      acc[a][2] = fmaf(xv[a].z, wv[2].z, acc[a][2]);
      acc[a][3] = fmaf(xv[a].z, wv[2].w, acc[a][3]);
      acc[a][0] = fmaf(xv[a].w, wv[3].x, acc[a][0]);
      acc[a][1] = fmaf(xv[a].w, wv[3].y, acc[a][1]);
      acc[a][2] = fmaf(xv[a].w, wv[3].z, acc[a][2]);
      acc[a][3] = fmaf(xv[a].w, wv[3].w, acc[a][3]);
    }
  }
  if (col0 < C2) {
#pragma unroll
    for (int a = 0; a < 4; ++a) {
      int node = node0 + ng * 4 + a;
      if (node < NN) {
        __half2 p01 = __floats2half2_rn(acc[a][0], acc[a][1]);
        __half2 p23 = __floats2half2_rn(acc[a][2], acc[a][3]);
        __half2* hp = (__half2*)&h2[(size_t)node * C2 + col0];
        hp[0] = p01; hp[1] = p23;
      }
    }
    float aw_s[4], aw_d[4];
#pragma unroll
    for (int j = 0; j < 4; ++j) { aw_s[j] = att_s[col0 + j]; aw_d[j] = att_d[col0 + j]; }
#pragma unroll
    for (int a = 0; a < 4; ++a) {
      float ps = acc[a][0]*aw_s[0] + acc[a][1]*aw_s[1] + acc[a][2]*aw_s[2] + acc[a][3]*aw_s[3];
      float pd = acc[a][0]*aw_d[0] + acc[a][1]*aw_d[1] + acc[a][2]*aw_d[2] + acc[a][3]*aw_d[3];
      atomicAdd(&sred_s[ng * 4 + a], ps);
      atomicAdd(&sred_d[ng * 4 + a], pd);
    }
  }
  __syncthreads();
  if (t < 64 && node0 + t < NN) { as[node0 + t] = sred_s[t]; ad[node0 + t] = sred_d[t]; }
}

// ---------- fused aggregation, layer 2 + bias + log_softmax: batched-8 ----------
__global__ __launch_bounds__(256) void agg2_kernel(
    const int* __restrict__ rowptr, const int* __restrict__ csr,
    const float* __restrict__ as, const float* __restrict__ ad,
    const __half* __restrict__ h2, const float* __restrict__ b2,
    float* __restrict__ out) {
  int node = blockIdx.x * 4 + (threadIdx.x >> 6);
  if (node >= NN) return;
  int lane = threadIdx.x & 63;
  int cl = min(lane, C2 - 1);    // lanes 40..63 duplicate col 39 (discarded)
  int beg = rowptr[node];
  int end = (node == NN - 1) ? ET : rowptr[node + 1];
  float adv = ad[node];
  float den = 0.f, acc = 0.f;
  for (int i = beg; i < end; i += 64) {
    int nch = min(64, end - i);
    int s64 = csr[i + min(lane, nch - 1)];
    int j = 0;
    for (; j + 8 <= nch; j += 8) {
      const __half* hr[8];
      float av[8], hv[8], ev[8];
#pragma unroll
      for (int r = 0; r < 8; ++r) {
        int sj = __builtin_amdgcn_readlane(s64, j + r);
        hr[r] = h2 + (size_t)sj * C2;
        av[r] = as[sj];                 // SGPR index -> scalar load
      }
#pragma unroll
      for (int r = 0; r < 8; ++r) hv[r] = __half2float(hr[r][cl]);
#pragma unroll
      for (int r = 0; r < 8; ++r) {
        float v = av[r] + adv;
        v = fmaxf(v, NEG * v);
        ev[r] = __expf(v);
      }
#pragma unroll
      for (int r = 0; r < 8; ++r) { den += ev[r]; acc = fmaf(hv[r], ev[r], acc); }
    }
    for (; j < nch; ++j) {
      int sj = __builtin_amdgcn_readlane(s64, j);
      float v = as[sj] + adv;
      v = fmaxf(v, NEG * v);
      float e = __expf(v);
      den += e;
      acc = fmaf(__half2float(h2[(size_t)sj * C2 + cl]), e, acc);
    }
  }
  float val = (lane < C2) ? acc / (den + EPSV) + b2[lane] : -INFINITY;
  float m2 = val;
#pragma unroll
  for (int off = 1; off < 64; off <<= 1) m2 = fmaxf(m2, __shfl_xor(m2, off, 64));
  float ex = (lane < C2) ? __expf(val - m2) : 0.f;
  float sum = ex;
#pragma unroll
  for (int off = 1; off < 64; off <<= 1) sum += __shfl_xor(sum, off, 64);
  if (lane < C2) out[(size_t)node * C2 + lane] = val - m2 - logf(sum);
}

// ---------- launch ----------
extern "C" void kernel_launch(void* const* d_in, const int* in_sizes, int n_in,
                              void* d_out, int out_size, void* d_ws, size_t ws_size,
                              hipStream_t stream) {
  const float* x    = (const float*)d_in[0];
  const float* W1   = (const float*)d_in[1];
  const float* as1w = (const float*)d_in[2];
  const float* ad1w = (const float*)d_in[3];
  const float* b1   = (const float*)d_in[4];
  const float* W2   = (const float*)d_in[5];
  const float* as2w = (const float*)d_in[6];
  const float* ad2w = (const float*)d_in[7];
  const float* b2   = (const float*)d_in[8];
  const int*   ei   = (const int*)d_in[9];

  float* out   = (float*)d_out;
  float* outls = out;                    // [N,40] log_softmax
  float* emb   = out + (long)NN * C2;    // [N,64] emb

  char* wsb = (char*)d_ws;
  __half* h1   = (__half*)wsb; wsb += sizeof(__half) * (size_t)NN * D1;
  __half* h2   = (__half*)wsb; wsb += sizeof(__half) * ((size_t)NN * C2 + 64);  // +64 pad
  float* asrc1 = (float*)wsb; wsb += sizeof(float) * (size_t)NN * H1;
  float* adst1 = (float*)wsb; wsb += sizeof(float) * (size_t)NN * H1;
  float* asrc2 = (float*)wsb; wsb += sizeof(float) * (size_t)NN;
  float* adst2 = (float*)wsb; wsb += sizeof(float) * (size_t)NN;
  int* rowptr  = (int*)wsb;   wsb += sizeof(int) * (size_t)NN;
  int* ghist   = (int*)wsb;   wsb += sizeof(int) * (NBKT + 4);
  int* bbase   = (int*)wsb;   wsb += sizeof(int) * (NBKT + 4);
  int* gcur    = (int*)wsb;   wsb += sizeof(int) * (NBKT + 4);
  int* barr    = (int*)wsb;   wsb += sizeof(int) * (size_t)ET;
  int* csr     = (int*)wsb;   wsb += sizeof(int) * (size_t)ET;

  // CSR build (bucketed; per call since ws is re-poisoned)
  hipMemsetAsync(ghist, 0, sizeof(int) * (NBKT + 4), stream);
  hipMemsetAsync(gcur, 0, sizeof(int) * (NBKT + 4), stream);
  hist_kernel<<<256, 256, 0, stream>>>(ei, ghist);
  bscan_kernel<<<1, 256, 0, stream>>>(ghist, bbase);
  scatter_kernel<<<NBB, 256, 0, stream>>>(ei, bbase, gcur, barr);
  bucket2csr_kernel<<<NBKT, 256, 0, stream>>>(barr, bbase, rowptr, csr);

  // layer 1
  gemm1_kernel<<<(NN + 63) / 64, 256, 0, stream>>>(x, W1, as1w, ad1w, h1, asrc1, adst1);
  agg1_kernel<<<(NN + 3) / 4, 256, 0, stream>>>(rowptr, csr, asrc1, adst1, h1, b1, emb);

  // layer 2 (gemm + attdot fused)
  gemm2_kernel<<<(NN + 63) / 64, 256, 0, stream>>>(emb, W2, as2w, ad2w, h2, asrc2, adst2);
  agg2_kernel<<<(NN + 3) / 4, 256, 0, stream>>>(rowptr, csr, asrc2, adst2, h2, b2, outls);
}